// Round 1
// baseline (1596.834 us; speedup 1.0000x reference)
//
#include <hip/hip_runtime.h>
#include <math.h>

#define D 128
#define EPS 1e-30f
#define LN_EPS 1e-5f

// ---- index dtype sniffing: harness may hand us int32 or int64 indices ----
__device__ inline bool idx_is_i64(const void* p, int n_nodes) {
    // If the data is really int64 (values in [0, n_nodes)), the first few
    // 64-bit words are all in range. If it's int32 data, a 64-bit read
    // combines two indices -> huge value unless the high word happens to be 0.
    const long long* q = (const long long*)p;
    bool ok = true;
#pragma unroll
    for (int i = 0; i < 4; ++i) {
        long long v = q[i];
        if (v < 0 || v >= (long long)n_nodes) ok = false;
    }
    return ok;
}

__device__ inline int load_idx(const void* p, long long e, bool is64) {
    if (is64) return (int)((const long long*)p)[e];
    return ((const int*)p)[e];
}

// ---- K1: scatter sum-of-exp + degree ----
// 32 threads per edge; each thread handles 4 contiguous dims (float4).
__global__ __launch_bounds__(256) void scatter_expsum(
        const float* __restrict__ x,
        const void* __restrict__ esrc_raw,
        const void* __restrict__ edst_raw,
        float* __restrict__ sumexp,   // [N,128], pre-zeroed
        int* __restrict__ deg,        // [N], pre-zeroed
        int E, int N) {
    long long tid = (long long)blockIdx.x * blockDim.x + threadIdx.x;
    long long total = (long long)E * 32;
    if (tid >= total) return;

    bool is64 = idx_is_i64(esrc_raw, N);  // same answer for all threads

    long long e = tid >> 5;
    int q = (int)(tid & 31);

    int s = load_idx(esrc_raw, e, is64);
    int d = load_idx(edst_raw, e, is64);

    const float4 v = *reinterpret_cast<const float4*>(x + (long long)s * D + q * 4);
    float* outp = sumexp + (long long)d * D + q * 4;
    atomicAdd(outp + 0, expf(v.x));
    atomicAdd(outp + 1, expf(v.y));
    atomicAdd(outp + 2, expf(v.z));
    atomicAdd(outp + 3, expf(v.w));
    if (q == 0) atomicAdd(deg + d, 1);
}

// ---- K2: fused concat-GEMM + LayerNorm + ReLU ----
// One block per node, 128 threads (one per output dim).
// sumexp aliases `out` (same buffer): we read row n fully before writing it.
__global__ __launch_bounds__(128) void gemm_ln_relu(
        const float* __restrict__ x,
        const float* __restrict__ sumexp,
        const int* __restrict__ deg,
        const float* __restrict__ W,      // [256,128] row-major
        const float* __restrict__ bias,
        const float* __restrict__ gamma,
        const float* __restrict__ beta,
        float* __restrict__ out) {
    const int n = blockIdx.x;
    const int t = threadIdx.x;

    __shared__ float v[2 * D];
    __shared__ float s_sum[2], s_sq[2];

    // stage concat([x[n], agg[n]]) in LDS
    v[t] = x[(long long)n * D + t];
    float se = sumexp[(long long)n * D + t];
    float agg = (deg[n] > 0) ? logf(fmaxf(se, EPS)) : 0.0f;
    v[D + t] = agg;
    __syncthreads();

    // 256-long dot product against W column t (coalesced across threads)
    float acc = bias[t];
#pragma unroll 8
    for (int k = 0; k < 2 * D; ++k) {
        acc += v[k] * W[k * D + t];
    }

    // LayerNorm reduction over 128 threads = 2 waves
    float sum = acc, sq = acc * acc;
#pragma unroll
    for (int o = 32; o > 0; o >>= 1) {
        sum += __shfl_xor(sum, o, 64);
        sq  += __shfl_xor(sq, o, 64);
    }
    int w = t >> 6;
    if ((t & 63) == 0) { s_sum[w] = sum; s_sq[w] = sq; }
    __syncthreads();
    float tsum = s_sum[0] + s_sum[1];
    float tsq  = s_sq[0] + s_sq[1];

    float mean = tsum * (1.0f / D);
    float var  = tsq * (1.0f / D) - mean * mean;
    float r = rsqrtf(var + LN_EPS);
    float y = (acc - mean) * r * gamma[t] + beta[t];
    out[(long long)n * D + t] = fmaxf(y, 0.0f);
}

extern "C" void kernel_launch(void* const* d_in, const int* in_sizes, int n_in,
                              void* d_out, int out_size, void* d_ws, size_t ws_size,
                              hipStream_t stream) {
    const float* x     = (const float*)d_in[0];
    const void*  esrc  = d_in[1];
    const void*  edst  = d_in[2];
    const float* W     = (const float*)d_in[3];
    const float* bias  = (const float*)d_in[4];
    const float* gamma = (const float*)d_in[5];
    const float* beta  = (const float*)d_in[6];

    const int E = in_sizes[1];
    const int N = in_sizes[0] / D;

    float* out    = (float*)d_out;
    float* sumexp = out;          // accumulate sum-of-exp in the output buffer
    int*   deg    = (int*)d_ws;   // N ints of scratch

    hipMemsetAsync(sumexp, 0, (size_t)N * D * sizeof(float), stream);
    hipMemsetAsync(deg, 0, (size_t)N * sizeof(int), stream);

    long long total = (long long)E * 32;
    int threads = 256;
    int blocks = (int)((total + threads - 1) / threads);
    scatter_expsum<<<blocks, threads, 0, stream>>>(x, esrc, edst, sumexp, deg, E, N);

    gemm_ln_relu<<<N, D, 0, stream>>>(x, sumexp, deg, W, bias, gamma, beta, out);
}

// Round 2
// 262.015 us; speedup vs baseline: 6.0944x; 6.0944x over previous
//
#include <hip/hip_runtime.h>
#include <math.h>

#define D 128
#define EPS 1e-30f
#define LN_EPS 1e-5f

typedef long long ll;

// ---- index dtype sniffing: harness may hand us int32 or int64 indices ----
__device__ inline bool idx_is_i64(const void* p, int n_nodes) {
    const ll* q = (const ll*)p;
    bool ok = true;
#pragma unroll
    for (int i = 0; i < 4; ++i) {
        ll v = q[i];
        if (v < 0 || v >= (ll)n_nodes) ok = false;
    }
    return ok;
}

__device__ inline int load_idx(const void* p, ll e, bool is64) {
    return is64 ? (int)((const ll*)p)[e] : ((const int*)p)[e];
}

// ======================= sort-based fast path =======================

// histogram of destinations
__global__ __launch_bounds__(256) void k_hist(const void* __restrict__ edst,
                                              int* __restrict__ deg, int E, int N) {
    bool is64 = idx_is_i64(edst, N);
    int i = blockIdx.x * 256 + threadIdx.x;
    if (i < E) atomicAdd(&deg[load_idx(edst, i, is64)], 1);
}

// block-level exclusive scan: each block covers 1024 elements (256 thr x 4)
__global__ __launch_bounds__(256) void k_scanA(const int* __restrict__ deg,
                                               int* __restrict__ off,
                                               int* __restrict__ bsum, int N) {
    __shared__ int s[256];
    int b = blockIdx.x, t = threadIdx.x;
    int base = b * 1024 + t * 4;
    int v0 = 0, v1 = 0, v2 = 0, v3 = 0;
    if (base + 0 < N) v0 = deg[base + 0];
    if (base + 1 < N) v1 = deg[base + 1];
    if (base + 2 < N) v2 = deg[base + 2];
    if (base + 3 < N) v3 = deg[base + 3];
    int loc = v0 + v1 + v2 + v3;
    s[t] = loc;
    __syncthreads();
    for (int o = 1; o < 256; o <<= 1) {
        int xv = (t >= o) ? s[t - o] : 0;
        __syncthreads();
        s[t] += xv;
        __syncthreads();
    }
    int run = s[t] - loc;  // exclusive prefix of this thread's chunk
    if (t == 255) bsum[b] = s[255];
    if (base + 0 < N) off[base + 0] = run; run += v0;
    if (base + 1 < N) off[base + 1] = run; run += v1;
    if (base + 2 < N) off[base + 2] = run; run += v2;
    if (base + 3 < N) off[base + 3] = run;
}

// scan of per-block sums (NB <= 256)
__global__ __launch_bounds__(256) void k_scanB(const int* __restrict__ bsum,
                                               int* __restrict__ bbase, int NB) {
    __shared__ int s[256];
    int t = threadIdx.x;
    int v = (t < NB) ? bsum[t] : 0;
    s[t] = v;
    __syncthreads();
    for (int o = 1; o < 256; o <<= 1) {
        int xv = (t >= o) ? s[t - o] : 0;
        __syncthreads();
        s[t] += xv;
        __syncthreads();
    }
    if (t < NB) bbase[t] = s[t] - v;
}

// add block bases; init scatter cursors
__global__ __launch_bounds__(256) void k_scanC(int* __restrict__ off,
                                               int* __restrict__ cur,
                                               const int* __restrict__ bbase, int N) {
    int b = blockIdx.x, t = threadIdx.x;
    int add = bbase[b];
    int base = b * 1024 + t * 4;
#pragma unroll
    for (int i = 0; i < 4; ++i) {
        int idx = base + i;
        if (idx < N) {
            int o = off[idx] + add;
            off[idx] = o;
            cur[idx] = o;
        }
    }
}

// scatter src ids into per-destination buckets (CSR)
__global__ __launch_bounds__(256) void k_scatter(const void* __restrict__ esrc,
                                                 const void* __restrict__ edst,
                                                 int* __restrict__ cur,
                                                 int* __restrict__ bucket, int E, int N) {
    bool is64s = idx_is_i64(esrc, N);
    bool is64d = idx_is_i64(edst, N);
    int i = blockIdx.x * 256 + threadIdx.x;
    if (i < E) {
        int s = load_idx(esrc, i, is64s);
        int d = load_idx(edst, i, is64d);
        int pos = atomicAdd(&cur[d], 1);
        bucket[pos] = s;
    }
}

// gather-side aggregation: one block (128 thr) per node; acc in registers
__global__ __launch_bounds__(128) void k_aggregate(const float* __restrict__ x,
                                                   const int* __restrict__ bucket,
                                                   const int* __restrict__ off,
                                                   const int* __restrict__ deg,
                                                   float* __restrict__ out) {
    int n = blockIdx.x, t = threadIdx.x;
    int start = __builtin_amdgcn_readfirstlane(off[n]);
    int dg    = __builtin_amdgcn_readfirstlane(deg[n]);
    int end = start + dg;
    float acc = 0.f;
    int e = start;
    for (; e + 1 < end; e += 2) {
        int s0 = __builtin_amdgcn_readfirstlane(bucket[e]);
        int s1 = __builtin_amdgcn_readfirstlane(bucket[e + 1]);
        float f0 = x[(ll)s0 * D + t];
        float f1 = x[(ll)s1 * D + t];
        acc += __expf(f0);
        acc += __expf(f1);
    }
    if (e < end) {
        int s0 = __builtin_amdgcn_readfirstlane(bucket[e]);
        acc += __expf(x[(ll)s0 * D + t]);
    }
    out[(ll)n * D + t] = (dg > 0) ? __logf(fmaxf(acc, EPS)) : 0.f;
}

// register-tiled GEMM + LayerNorm + ReLU.
// 32 rows/block, 256 threads: tx in [0,32) owns 4 output dims, ty in [0,8) owns 4 rows.
// `io` holds agg (from k_aggregate) on input rows; overwritten with the result.
__global__ __launch_bounds__(256) void k_gemm(const float* __restrict__ x,
                                              const float* __restrict__ W,
                                              const float* __restrict__ bias,
                                              const float* __restrict__ gamma,
                                              const float* __restrict__ beta,
                                              float* io, int N) {
    __shared__ float v[32][256];
    int n0 = blockIdx.x * 32;
    int t = threadIdx.x;
    int tx = t & 31, ty = t >> 5;

    // stage concat([x rows, agg rows]) : 32 KB, float4 loads
#pragma unroll
    for (int i = 0; i < 8; ++i) {
        int idx = i * 256 + t;
        int r = idx >> 6;       // 0..31
        int c4 = idx & 63;      // float4 slot within 256-float row
        int n = n0 + r;
        float4 val = make_float4(0.f, 0.f, 0.f, 0.f);
        if (n < N) {
            if (c4 < 32) val = *(const float4*)&x[(ll)n * D + c4 * 4];
            else         val = *(const float4*)&io[(ll)n * D + (c4 - 32) * 4];
        }
        *(float4*)&v[r][c4 * 4] = val;
    }
    __syncthreads();

    float4 bb = *(const float4*)&bias[tx * 4];
    float acc[4][4];
#pragma unroll
    for (int i = 0; i < 4; ++i) {
        acc[i][0] = bb.x; acc[i][1] = bb.y; acc[i][2] = bb.z; acc[i][3] = bb.w;
    }

    for (int k = 0; k < 256; k += 4) {
        float4 w0 = *(const float4*)&W[(k + 0) * D + tx * 4];
        float4 w1 = *(const float4*)&W[(k + 1) * D + tx * 4];
        float4 w2 = *(const float4*)&W[(k + 2) * D + tx * 4];
        float4 w3 = *(const float4*)&W[(k + 3) * D + tx * 4];
#pragma unroll
        for (int i = 0; i < 4; ++i) {
            float4 vv = *(const float4*)&v[ty * 4 + i][k];
            acc[i][0] += vv.x * w0.x + vv.y * w1.x + vv.z * w2.x + vv.w * w3.x;
            acc[i][1] += vv.x * w0.y + vv.y * w1.y + vv.z * w2.y + vv.w * w3.y;
            acc[i][2] += vv.x * w0.z + vv.y * w1.z + vv.z * w2.z + vv.w * w3.z;
            acc[i][3] += vv.x * w0.w + vv.y * w1.w + vv.z * w2.w + vv.w * w3.w;
        }
    }

    float4 g  = *(const float4*)&gamma[tx * 4];
    float4 be = *(const float4*)&beta[tx * 4];
#pragma unroll
    for (int i = 0; i < 4; ++i) {
        int n = n0 + ty * 4 + i;
        float s = acc[i][0] + acc[i][1] + acc[i][2] + acc[i][3];
        float q = acc[i][0] * acc[i][0] + acc[i][1] * acc[i][1] +
                  acc[i][2] * acc[i][2] + acc[i][3] * acc[i][3];
#pragma unroll
        for (int o = 1; o < 32; o <<= 1) {
            s += __shfl_xor(s, o, 64);
            q += __shfl_xor(q, o, 64);
        }
        float mean = s * (1.f / D);
        float var  = q * (1.f / D) - mean * mean;
        float rin  = rsqrtf(var + LN_EPS);
        if (n < N) {
            float4 y;
            y.x = fmaxf((acc[i][0] - mean) * rin * g.x + be.x, 0.f);
            y.y = fmaxf((acc[i][1] - mean) * rin * g.y + be.y, 0.f);
            y.z = fmaxf((acc[i][2] - mean) * rin * g.z + be.z, 0.f);
            y.w = fmaxf((acc[i][3] - mean) * rin * g.w + be.w, 0.f);
            *(float4*)&io[(ll)n * D + tx * 4] = y;
        }
    }
}

// ======================= fallback (round-1) path =======================

__global__ __launch_bounds__(256) void scatter_expsum(
        const float* __restrict__ x, const void* __restrict__ esrc_raw,
        const void* __restrict__ edst_raw, float* __restrict__ sumexp,
        int* __restrict__ deg, int E, int N) {
    ll tid = (ll)blockIdx.x * blockDim.x + threadIdx.x;
    ll total = (ll)E * 32;
    if (tid >= total) return;
    bool is64 = idx_is_i64(esrc_raw, N);
    ll e = tid >> 5;
    int q = (int)(tid & 31);
    int s = load_idx(esrc_raw, e, is64);
    int d = load_idx(edst_raw, e, is64);
    const float4 v = *reinterpret_cast<const float4*>(x + (ll)s * D + q * 4);
    float* outp = sumexp + (ll)d * D + q * 4;
    atomicAdd(outp + 0, expf(v.x));
    atomicAdd(outp + 1, expf(v.y));
    atomicAdd(outp + 2, expf(v.z));
    atomicAdd(outp + 3, expf(v.w));
    if (q == 0) atomicAdd(deg + d, 1);
}

__global__ __launch_bounds__(128) void gemm_ln_relu_fb(
        const float* __restrict__ x, const float* __restrict__ sumexp,
        const int* __restrict__ deg, const float* __restrict__ W,
        const float* __restrict__ bias, const float* __restrict__ gamma,
        const float* __restrict__ beta, float* __restrict__ out) {
    const int n = blockIdx.x;
    const int t = threadIdx.x;
    __shared__ float v[2 * D];
    __shared__ float s_sum[2], s_sq[2];
    v[t] = x[(ll)n * D + t];
    float se = sumexp[(ll)n * D + t];
    v[D + t] = (deg[n] > 0) ? logf(fmaxf(se, EPS)) : 0.0f;
    __syncthreads();
    float acc = bias[t];
#pragma unroll 8
    for (int k = 0; k < 2 * D; ++k) acc += v[k] * W[k * D + t];
    float sum = acc, sq = acc * acc;
#pragma unroll
    for (int o = 32; o > 0; o >>= 1) {
        sum += __shfl_xor(sum, o, 64);
        sq  += __shfl_xor(sq, o, 64);
    }
    int w = t >> 6;
    if ((t & 63) == 0) { s_sum[w] = sum; s_sq[w] = sq; }
    __syncthreads();
    float mean = (s_sum[0] + s_sum[1]) * (1.0f / D);
    float var  = (s_sq[0] + s_sq[1]) * (1.0f / D) - mean * mean;
    float r = rsqrtf(var + LN_EPS);
    float y = (acc - mean) * r * gamma[t] + beta[t];
    out[(ll)n * D + t] = fmaxf(y, 0.0f);
}

// ======================= launch =======================

extern "C" void kernel_launch(void* const* d_in, const int* in_sizes, int n_in,
                              void* d_out, int out_size, void* d_ws, size_t ws_size,
                              hipStream_t stream) {
    const float* x     = (const float*)d_in[0];
    const void*  esrc  = d_in[1];
    const void*  edst  = d_in[2];
    const float* W     = (const float*)d_in[3];
    const float* bias  = (const float*)d_in[4];
    const float* gamma = (const float*)d_in[5];
    const float* beta  = (const float*)d_in[6];

    const int E = in_sizes[1];
    const int N = in_sizes[0] / D;
    float* out = (float*)d_out;

    const int NB = (N + 1023) / 1024;
    size_t need = ((size_t)3 * N + 512 + (size_t)E) * sizeof(int);

    if (ws_size >= need && NB <= 256) {
        int* deg    = (int*)d_ws;
        int* off    = deg + N;
        int* cur    = off + N;
        int* bsum   = cur + N;
        int* bbase  = bsum + 256;
        int* bucket = bbase + 256;

        hipMemsetAsync(deg, 0, (size_t)N * sizeof(int), stream);
        int eb = (E + 255) / 256;
        k_hist<<<eb, 256, 0, stream>>>(edst, deg, E, N);
        k_scanA<<<NB, 256, 0, stream>>>(deg, off, bsum, N);
        k_scanB<<<1, 256, 0, stream>>>(bsum, bbase, NB);
        k_scanC<<<NB, 256, 0, stream>>>(off, cur, bbase, N);
        k_scatter<<<eb, 256, 0, stream>>>(esrc, edst, cur, bucket, E, N);
        k_aggregate<<<N, 128, 0, stream>>>(x, bucket, off, deg, out);
        int gb = (N + 31) / 32;
        k_gemm<<<gb, 256, 0, stream>>>(x, W, bias, gamma, beta, out, N);
    } else {
        // fallback: atomic scatter path
        float* sumexp = out;
        int* deg = (int*)d_ws;
        hipMemsetAsync(sumexp, 0, (size_t)N * D * sizeof(float), stream);
        hipMemsetAsync(deg, 0, (size_t)N * sizeof(int), stream);
        ll total = (ll)E * 32;
        int blocks = (int)((total + 255) / 256);
        scatter_expsum<<<blocks, 256, 0, stream>>>(x, esrc, edst, sumexp, deg, E, N);
        gemm_ln_relu_fb<<<N, D, 0, stream>>>(x, sumexp, deg, W, bias, gamma, beta, out);
    }
}

// Round 3
// 195.448 us; speedup vs baseline: 8.1701x; 1.3406x over previous
//
#include <hip/hip_runtime.h>
#include <math.h>

#define D 128
#define EPS 1e-30f
#define LN_EPS 1e-5f

typedef long long ll;
typedef __attribute__((ext_vector_type(8))) short short8;
typedef __attribute__((ext_vector_type(4))) float f32x4;

// round-to-nearest-even f32 -> bf16
__device__ inline unsigned short f2bf(float f) {
    unsigned int u = __float_as_uint(f);
    u += 0x7FFF + ((u >> 16) & 1);
    return (unsigned short)(u >> 16);
}

// ---- index dtype sniffing: harness may hand us int32 or int64 indices ----
__device__ inline bool idx_is_i64(const void* p, int n_nodes) {
    const ll* q = (const ll*)p;
    bool ok = true;
#pragma unroll
    for (int i = 0; i < 4; ++i) {
        ll v = q[i];
        if (v < 0 || v >= (ll)n_nodes) ok = false;
    }
    return ok;
}

__device__ inline int load_idx(const void* p, ll e, bool is64) {
    return is64 ? (int)((const ll*)p)[e] : ((const int*)p)[e];
}

// ======================= sort-based fast path =======================

__global__ __launch_bounds__(256) void k_hist(const void* __restrict__ edst,
                                              int* __restrict__ deg, int E, int N) {
    bool is64 = idx_is_i64(edst, N);
    int i = blockIdx.x * 256 + threadIdx.x;
    if (i < E) atomicAdd(&deg[load_idx(edst, i, is64)], 1);
}

__global__ __launch_bounds__(256) void k_scanA(const int* __restrict__ deg,
                                               int* __restrict__ off,
                                               int* __restrict__ bsum, int N) {
    __shared__ int s[256];
    int b = blockIdx.x, t = threadIdx.x;
    int base = b * 1024 + t * 4;
    int v0 = 0, v1 = 0, v2 = 0, v3 = 0;
    if (base + 0 < N) v0 = deg[base + 0];
    if (base + 1 < N) v1 = deg[base + 1];
    if (base + 2 < N) v2 = deg[base + 2];
    if (base + 3 < N) v3 = deg[base + 3];
    int loc = v0 + v1 + v2 + v3;
    s[t] = loc;
    __syncthreads();
    for (int o = 1; o < 256; o <<= 1) {
        int xv = (t >= o) ? s[t - o] : 0;
        __syncthreads();
        s[t] += xv;
        __syncthreads();
    }
    int run = s[t] - loc;
    if (t == 255) bsum[b] = s[255];
    if (base + 0 < N) off[base + 0] = run; run += v0;
    if (base + 1 < N) off[base + 1] = run; run += v1;
    if (base + 2 < N) off[base + 2] = run; run += v2;
    if (base + 3 < N) off[base + 3] = run;
}

__global__ __launch_bounds__(256) void k_scanB(const int* __restrict__ bsum,
                                               int* __restrict__ bbase, int NB) {
    __shared__ int s[256];
    int t = threadIdx.x;
    int v = (t < NB) ? bsum[t] : 0;
    s[t] = v;
    __syncthreads();
    for (int o = 1; o < 256; o <<= 1) {
        int xv = (t >= o) ? s[t - o] : 0;
        __syncthreads();
        s[t] += xv;
        __syncthreads();
    }
    if (t < NB) bbase[t] = s[t] - v;
}

__global__ __launch_bounds__(256) void k_scanC(int* __restrict__ off,
                                               int* __restrict__ cur,
                                               const int* __restrict__ bbase, int N) {
    int b = blockIdx.x, t = threadIdx.x;
    int add = bbase[b];
    int base = b * 1024 + t * 4;
#pragma unroll
    for (int i = 0; i < 4; ++i) {
        int idx = base + i;
        if (idx < N) {
            int o = off[idx] + add;
            off[idx] = o;
            cur[idx] = o;
        }
    }
}

__global__ __launch_bounds__(256) void k_scatter(const void* __restrict__ esrc,
                                                 const void* __restrict__ edst,
                                                 int* __restrict__ cur,
                                                 int* __restrict__ bucket, int E, int N) {
    bool is64s = idx_is_i64(esrc, N);
    bool is64d = idx_is_i64(edst, N);
    int i = blockIdx.x * 256 + threadIdx.x;
    if (i < E) {
        int s = load_idx(esrc, i, is64s);
        int d = load_idx(edst, i, is64d);
        int pos = atomicAdd(&cur[d], 1);
        bucket[pos] = s;
    }
}

// gather-side aggregation; emits the MFMA A-operand: A[n][0:128]=bf16(x[n]),
// A[n][128:256]=bf16(agg[n]).  A lives in d_out (bf16 [N][256] = 25.6 MB).
__global__ __launch_bounds__(128) void k_aggregate(const float* __restrict__ x,
                                                   const int* __restrict__ bucket,
                                                   const int* __restrict__ off,
                                                   const int* __restrict__ deg,
                                                   unsigned short* __restrict__ A) {
    int n = blockIdx.x, t = threadIdx.x;
    int start = __builtin_amdgcn_readfirstlane(off[n]);
    int dg    = __builtin_amdgcn_readfirstlane(deg[n]);
    int end = start + dg;
    float acc = 0.f;
    int e = start;
    for (; e + 3 < end; e += 4) {
        int s0 = __builtin_amdgcn_readfirstlane(bucket[e]);
        int s1 = __builtin_amdgcn_readfirstlane(bucket[e + 1]);
        int s2 = __builtin_amdgcn_readfirstlane(bucket[e + 2]);
        int s3 = __builtin_amdgcn_readfirstlane(bucket[e + 3]);
        float f0 = x[(ll)s0 * D + t];
        float f1 = x[(ll)s1 * D + t];
        float f2 = x[(ll)s2 * D + t];
        float f3 = x[(ll)s3 * D + t];
        acc += __expf(f0) + __expf(f1) + __expf(f2) + __expf(f3);
    }
    for (; e < end; ++e) {
        int s0 = __builtin_amdgcn_readfirstlane(bucket[e]);
        acc += __expf(x[(ll)s0 * D + t]);
    }
    float agg = (dg > 0) ? __logf(fmaxf(acc, EPS)) : 0.f;
    A[(ll)n * 256 + t]       = f2bf(x[(ll)n * D + t]);
    A[(ll)n * 256 + 128 + t] = f2bf(agg);
}

// W [256][128] f32 -> WT [128][256] bf16 (transposed so B-frags are contiguous)
__global__ __launch_bounds__(256) void k_wt(const float* __restrict__ W,
                                            unsigned short* __restrict__ WT) {
    int idx = blockIdx.x * 256 + threadIdx.x;   // 32768 total
    int k = idx >> 7, n = idx & 127;
    WT[n * 256 + k] = f2bf(W[idx]);
}

// MFMA GEMM + LayerNorm + ReLU.  A (bf16 [N][256]) aliases out (f32 [N][128]):
// each block stages its own 64 rows into LDS before overwriting them.
__global__ __launch_bounds__(256) void k_gemm_mfma(
        const unsigned short* __restrict__ A,
        const unsigned short* __restrict__ WT,
        const float* __restrict__ bias,
        const float* __restrict__ gamma,
        const float* __restrict__ beta,
        float* __restrict__ out, int N) {
    __shared__ unsigned char sA[64 * 512];   // [64 rows][256 bf16], XOR-swizzled
    __shared__ float2 sPart[2][64];          // per-col-half {sum, sumsq} per row
    int t = threadIdx.x;
    int l = t & 63, w = t >> 6;
    int wr = w >> 1, wc = w & 1;
    int n0 = blockIdx.x * 64;

    // ---- stage A tile (32 KB), swizzle byte ^= (row&7)<<4 ----
    const uint4* gA = (const uint4*)(A + (ll)n0 * 256);
#pragma unroll
    for (int i = 0; i < 8; ++i) {
        int c = i * 256 + t;
        int row = c >> 5, cc = c & 31;
        uint4 v = make_uint4(0u, 0u, 0u, 0u);
        if (n0 + row < N) v = gA[row * 32 + cc];
        *(uint4*)(sA + row * 512 + ((cc * 16) ^ ((row & 7) << 4))) = v;
    }
    __syncthreads();

    f32x4 acc[2][4];
#pragma unroll
    for (int m = 0; m < 2; ++m)
#pragma unroll
        for (int n = 0; n < 4; ++n) acc[m][n] = (f32x4){0.f, 0.f, 0.f, 0.f};

    const int lr = l & 15, lk = l >> 4;
    const int aswz = (lr & 7) << 4;          // (row&7)<<4 with row = ..16m + lr
    const unsigned short* wbase = WT + (wc * 64 + lr) * 256 + lk * 8;

#pragma unroll
    for (int ks = 0; ks < 8; ++ks) {
        short8 a[2], b[4];
#pragma unroll
        for (int m = 0; m < 2; ++m) {
            int arow = wr * 32 + m * 16 + lr;
            a[m] = *(const short8*)(sA + arow * 512 + ((ks * 64 + lk * 16) ^ aswz));
        }
#pragma unroll
        for (int n = 0; n < 4; ++n)
            b[n] = *(const short8*)(wbase + n * 16 * 256 + ks * 32);
#pragma unroll
        for (int m = 0; m < 2; ++m)
#pragma unroll
            for (int n = 0; n < 4; ++n)
                acc[m][n] = __builtin_amdgcn_mfma_f32_16x16x32_bf16(a[m], b[n], acc[m][n], 0, 0, 0);
    }

    // ---- fused LayerNorm epilogue, no h round-trip ----
    const int col_base = wc * 64 + lr;
    float bn[4], gn[4], ben[4];
#pragma unroll
    for (int n = 0; n < 4; ++n) {
        int col = col_base + n * 16;
        bn[n] = bias[col]; gn[n] = gamma[col]; ben[n] = beta[col];
    }
#pragma unroll
    for (int m = 0; m < 2; ++m) {
#pragma unroll
        for (int r = 0; r < 4; ++r) {
            float s = 0.f, q = 0.f;
#pragma unroll
            for (int n = 0; n < 4; ++n) {
                float v = acc[m][n][r] + bn[n];
                acc[m][n][r] = v;
                s += v; q += v * v;
            }
#pragma unroll
            for (int o = 1; o < 16; o <<= 1) {   // reduce over the 16-lane col group
                s += __shfl_xor(s, o, 64);
                q += __shfl_xor(q, o, 64);
            }
            if (lr == 0) {
                int rowl = wr * 32 + m * 16 + lk * 4 + r;
                sPart[wc][rowl] = make_float2(s, q);
            }
        }
    }
    __syncthreads();
#pragma unroll
    for (int m = 0; m < 2; ++m) {
#pragma unroll
        for (int r = 0; r < 4; ++r) {
            int rowl = wr * 32 + m * 16 + lk * 4 + r;
            float2 p0 = sPart[0][rowl], p1 = sPart[1][rowl];
            float ssum = p0.x + p1.x, qsum = p0.y + p1.y;
            float mean = ssum * (1.f / 128.f);
            float var  = qsum * (1.f / 128.f) - mean * mean;
            float rstd = rsqrtf(var + LN_EPS);
            int grow = n0 + rowl;
            if (grow < N) {
                float* op = out + (ll)grow * 128;
#pragma unroll
                for (int n = 0; n < 4; ++n) {
                    float y = (acc[m][n][r] - mean) * rstd * gn[n] + ben[n];
                    op[col_base + n * 16] = fmaxf(y, 0.f);
                }
            }
        }
    }
}

// ======================= fallback (atomic) path =======================

__global__ __launch_bounds__(256) void scatter_expsum(
        const float* __restrict__ x, const void* __restrict__ esrc_raw,
        const void* __restrict__ edst_raw, float* __restrict__ sumexp,
        int* __restrict__ deg, int E, int N) {
    ll tid = (ll)blockIdx.x * blockDim.x + threadIdx.x;
    ll total = (ll)E * 32;
    if (tid >= total) return;
    bool is64 = idx_is_i64(esrc_raw, N);
    ll e = tid >> 5;
    int q = (int)(tid & 31);
    int s = load_idx(esrc_raw, e, is64);
    int d = load_idx(edst_raw, e, is64);
    const float4 v = *reinterpret_cast<const float4*>(x + (ll)s * D + q * 4);
    float* outp = sumexp + (ll)d * D + q * 4;
    atomicAdd(outp + 0, expf(v.x));
    atomicAdd(outp + 1, expf(v.y));
    atomicAdd(outp + 2, expf(v.z));
    atomicAdd(outp + 3, expf(v.w));
    if (q == 0) atomicAdd(deg + d, 1);
}

__global__ __launch_bounds__(128) void gemm_ln_relu_fb(
        const float* __restrict__ x, const float* __restrict__ sumexp,
        const int* __restrict__ deg, const float* __restrict__ W,
        const float* __restrict__ bias, const float* __restrict__ gamma,
        const float* __restrict__ beta, float* __restrict__ out) {
    const int n = blockIdx.x;
    const int t = threadIdx.x;
    __shared__ float v[2 * D];
    __shared__ float s_sum[2], s_sq[2];
    v[t] = x[(ll)n * D + t];
    float se = sumexp[(ll)n * D + t];
    v[D + t] = (deg[n] > 0) ? logf(fmaxf(se, EPS)) : 0.0f;
    __syncthreads();
    float acc = bias[t];
#pragma unroll 8
    for (int k = 0; k < 2 * D; ++k) acc += v[k] * W[k * D + t];
    float sum = acc, sq = acc * acc;
#pragma unroll
    for (int o = 32; o > 0; o >>= 1) {
        sum += __shfl_xor(sum, o, 64);
        sq  += __shfl_xor(sq, o, 64);
    }
    int w = t >> 6;
    if ((t & 63) == 0) { s_sum[w] = sum; s_sq[w] = sq; }
    __syncthreads();
    float mean = (s_sum[0] + s_sum[1]) * (1.0f / D);
    float var  = (s_sq[0] + s_sq[1]) * (1.0f / D) - mean * mean;
    float r = rsqrtf(var + LN_EPS);
    float y = (acc - mean) * r * gamma[t] + beta[t];
    out[(ll)n * D + t] = fmaxf(y, 0.0f);
}

// ======================= launch =======================

extern "C" void kernel_launch(void* const* d_in, const int* in_sizes, int n_in,
                              void* d_out, int out_size, void* d_ws, size_t ws_size,
                              hipStream_t stream) {
    const float* x     = (const float*)d_in[0];
    const void*  esrc  = d_in[1];
    const void*  edst  = d_in[2];
    const float* W     = (const float*)d_in[3];
    const float* bias  = (const float*)d_in[4];
    const float* gamma = (const float*)d_in[5];
    const float* beta  = (const float*)d_in[6];

    const int E = in_sizes[1];
    const int N = in_sizes[0] / D;
    float* out = (float*)d_out;

    const int NB = (N + 1023) / 1024;
    size_t need = ((size_t)3 * N + 512 + (size_t)E + 16384) * sizeof(int);

    if (ws_size >= need && NB <= 256) {
        int* deg    = (int*)d_ws;
        int* off    = deg + N;
        int* cur    = off + N;
        int* bsum   = cur + N;
        int* bbase  = bsum + 256;
        int* bucket = bbase + 256;
        unsigned short* wt = (unsigned short*)(bucket + E);

        hipMemsetAsync(deg, 0, (size_t)N * sizeof(int), stream);
        int eb = (E + 255) / 256;
        k_wt<<<128, 256, 0, stream>>>(W, wt);
        k_hist<<<eb, 256, 0, stream>>>(edst, deg, E, N);
        k_scanA<<<NB, 256, 0, stream>>>(deg, off, bsum, N);
        k_scanB<<<1, 256, 0, stream>>>(bsum, bbase, NB);
        k_scanC<<<NB, 256, 0, stream>>>(off, cur, bbase, N);
        k_scatter<<<eb, 256, 0, stream>>>(esrc, edst, cur, bucket, E, N);
        k_aggregate<<<N, 128, 0, stream>>>(x, bucket, off, deg, (unsigned short*)out);
        int gb = (N + 63) / 64;
        k_gemm_mfma<<<gb, 256, 0, stream>>>((const unsigned short*)out, wt,
                                            bias, gamma, beta, out, N);
    } else {
        float* sumexp = out;
        int* deg = (int*)d_ws;
        hipMemsetAsync(sumexp, 0, (size_t)N * D * sizeof(float), stream);
        hipMemsetAsync(deg, 0, (size_t)N * sizeof(int), stream);
        ll total = (ll)E * 32;
        int blocks = (int)((total + 255) / 256);
        scatter_expsum<<<blocks, 256, 0, stream>>>(x, esrc, edst, sumexp, deg, E, N);
        gemm_ln_relu_fb<<<N, D, 0, stream>>>(x, sumexp, deg, W, bias, gamma, beta, out);
    }
}

// Round 4
// 135.999 us; speedup vs baseline: 11.7415x; 1.4371x over previous
//
#include <hip/hip_runtime.h>
#include <math.h>

#define D 128
#define EPS 1e-30f
#define LN_EPS 1e-5f

#define BINSHIFT 9
#define BINW 512
#define NBIN_MAX 128
#define P1_EPB 4096

typedef long long ll;
typedef __attribute__((ext_vector_type(8))) short short8;
typedef __attribute__((ext_vector_type(4))) float f32x4;

// round-to-nearest-even f32 -> bf16
__device__ inline unsigned short f2bf(float f) {
    unsigned int u = __float_as_uint(f);
    u += 0x7FFF + ((u >> 16) & 1);
    return (unsigned short)(u >> 16);
}

__device__ inline float bf2f_lo(unsigned int w) { return __uint_as_float(w << 16); }
__device__ inline float bf2f_hi(unsigned int w) { return __uint_as_float(w & 0xFFFF0000u); }

// ---- index dtype sniffing: harness may hand us int32 or int64 indices ----
__device__ inline bool idx_is_i64(const void* p, int n_nodes) {
    const ll* q = (const ll*)p;
    bool ok = true;
#pragma unroll
    for (int i = 0; i < 4; ++i) {
        ll v = q[i];
        if (v < 0 || v >= (ll)n_nodes) ok = false;
    }
    return ok;
}

__device__ inline int load_idx(const void* p, ll e, bool is64) {
    return is64 ? (int)((const ll*)p)[e] : ((const int*)p)[e];
}

// ======================= new fast path (N <= 65536) =======================

// x -> bf16 into A's left half (A = [N][256] bf16, lives in d_out)
__global__ __launch_bounds__(256) void k_prep(const float* __restrict__ x,
                                              unsigned short* __restrict__ A, int N) {
    int i = blockIdx.x * 256 + threadIdx.x;  // one float4 per thread
    if (i >= N * 32) return;
    int n = i >> 5, c4 = i & 31;
    float4 v = *(const float4*)(x + (ll)n * D + c4 * 4);
    ushort4 o;
    o.x = f2bf(v.x); o.y = f2bf(v.y); o.z = f2bf(v.z); o.w = f2bf(v.w);
    *(ushort4*)(A + (ll)n * 256 + c4 * 4) = o;
}

// W [256][128] f32 -> WT [128][256] bf16
__global__ __launch_bounds__(256) void k_wt(const float* __restrict__ W,
                                            unsigned short* __restrict__ WT) {
    int idx = blockIdx.x * 256 + threadIdx.x;
    int k = idx >> 7, n = idx & 127;
    WT[n * 256 + k] = f2bf(W[idx]);
}

// coarse-bin histogram (bin = dst >> 9)
__global__ __launch_bounds__(256) void k_pass1a(const void* __restrict__ edst,
                                                int* __restrict__ bincnt, int E, int N) {
    __shared__ int hist[NBIN_MAX];
    bool is64 = idx_is_i64(edst, N);
    int t = threadIdx.x;
    if (t < NBIN_MAX) hist[t] = 0;
    __syncthreads();
    ll base = (ll)blockIdx.x * P1_EPB;
    int cnt = (int)min((ll)P1_EPB, (ll)E - base);
    for (int i = t; i < cnt; i += 256) {
        int d = load_idx(edst, base + i, is64);
        atomicAdd(&hist[d >> BINSHIFT], 1);
    }
    __syncthreads();
    if (t < NBIN_MAX && hist[t]) atomicAdd(&bincnt[t], hist[t]);
}

// scan of bin counts -> pbase/pcur; sentinels
__global__ __launch_bounds__(NBIN_MAX) void k_binscan(const int* __restrict__ bincnt,
                                                      int* __restrict__ pbase,
                                                      int* __restrict__ pcur,
                                                      int* __restrict__ off, int E, int N) {
    __shared__ int s[NBIN_MAX];
    int t = threadIdx.x;
    int v = bincnt[t];
    s[t] = v;
    __syncthreads();
    for (int o = 1; o < NBIN_MAX; o <<= 1) {
        int xv = (t >= o) ? s[t - o] : 0;
        __syncthreads();
        s[t] += xv;
        __syncthreads();
    }
    pbase[t] = s[t] - v;
    pcur[t]  = s[t] - v;
    if (t == NBIN_MAX - 1) { pbase[NBIN_MAX] = s[t]; off[N] = E; }
}

// bin edges into coarse bins as packed (dst<<16)|src pairs
__global__ __launch_bounds__(256) void k_pass1b(const void* __restrict__ esrc,
                                                const void* __restrict__ edst,
                                                int* __restrict__ pcur,
                                                unsigned int* __restrict__ pairs,
                                                int E, int N) {
    __shared__ unsigned int sp[P1_EPB];   // 16 KB
    __shared__ int hist[NBIN_MAX];
    __shared__ int curs[NBIN_MAX];
    bool is64s = idx_is_i64(esrc, N);
    bool is64d = idx_is_i64(edst, N);
    int t = threadIdx.x;
    if (t < NBIN_MAX) hist[t] = 0;
    __syncthreads();
    ll base = (ll)blockIdx.x * P1_EPB;
    int cnt = (int)min((ll)P1_EPB, (ll)E - base);
    for (int i = t; i < cnt; i += 256) {
        unsigned int s = (unsigned int)load_idx(esrc, base + i, is64s);
        unsigned int d = (unsigned int)load_idx(edst, base + i, is64d);
        sp[i] = (d << 16) | s;
        atomicAdd(&hist[d >> BINSHIFT], 1);
    }
    __syncthreads();
    if (t < NBIN_MAX) curs[t] = hist[t] ? atomicAdd(&pcur[t], hist[t]) : 0;
    __syncthreads();
    for (int i = t; i < cnt; i += 256) {
        unsigned int p = sp[i];
        int b = p >> (16 + BINSHIFT);
        int pos = atomicAdd(&curs[b], 1);
        pairs[pos] = p;
    }
}

// per-bin: node-level CSR offsets + u16 src bucket (writes stay in an L2-hot window)
__global__ __launch_bounds__(256) void k_pass2(const unsigned int* __restrict__ pairs,
                                               const int* __restrict__ pbase,
                                               int* __restrict__ off,
                                               unsigned short* __restrict__ bucket, int N) {
    __shared__ int dhist[BINW];
    __shared__ int dcur[BINW];
    __shared__ int ssum[256];
    int b = blockIdx.x, t = threadIdx.x;
    int p0 = pbase[b], p1 = pbase[b + 1];
    int n0 = b << BINSHIFT;
    for (int j = t; j < BINW; j += 256) dhist[j] = 0;
    __syncthreads();
    for (int i = p0 + t; i < p1; i += 256)
        atomicAdd(&dhist[(pairs[i] >> 16) & (BINW - 1)], 1);
    __syncthreads();
    // exclusive scan of dhist[512] with 256 threads
    int h0 = dhist[2 * t], h1 = dhist[2 * t + 1];
    int loc = h0 + h1;
    ssum[t] = loc;
    __syncthreads();
    for (int o = 1; o < 256; o <<= 1) {
        int xv = (t >= o) ? ssum[t - o] : 0;
        __syncthreads();
        ssum[t] += xv;
        __syncthreads();
    }
    int ex = ssum[t] - loc;
    dcur[2 * t]     = ex;
    dcur[2 * t + 1] = ex + h0;
    __syncthreads();
    int lim = min(BINW, N - n0);
    for (int j = t; j < lim; j += 256) off[n0 + j] = p0 + dcur[j];
    __syncthreads();
    for (int i = p0 + t; i < p1; i += 256) {
        unsigned int p = pairs[i];
        int dl = (p >> 16) & (BINW - 1);
        int pos = p0 + atomicAdd(&dcur[dl], 1);
        bucket[pos] = (unsigned short)(p & 0xFFFFu);
    }
}

// gather-side aggregation: 1 wave per node, 16-lane x 16B coalesced bf16 row reads.
// Reads A's left halves (random rows), writes own row's right half.
__global__ __launch_bounds__(256) void k_aggregate(const int* __restrict__ off,
                                                   const unsigned short* __restrict__ bucket,
                                                   unsigned short* __restrict__ A, int N) {
    int w = threadIdx.x >> 6, lane = threadIdx.x & 63;
    int n = blockIdx.x * 4 + w;
    if (n >= N) return;
    int start = off[n], end = off[n + 1];
    int sub = lane >> 4, c16 = lane & 15;
    float acc[8];
#pragma unroll
    for (int j = 0; j < 8; ++j) acc[j] = 0.f;
    for (int e = start + sub; e < end; e += 4) {
        int src = bucket[e];
        uint4 v = *(const uint4*)(A + (ll)src * 256 + c16 * 8);
        acc[0] += __expf(bf2f_lo(v.x)); acc[1] += __expf(bf2f_hi(v.x));
        acc[2] += __expf(bf2f_lo(v.y)); acc[3] += __expf(bf2f_hi(v.y));
        acc[4] += __expf(bf2f_lo(v.z)); acc[5] += __expf(bf2f_hi(v.z));
        acc[6] += __expf(bf2f_lo(v.w)); acc[7] += __expf(bf2f_hi(v.w));
    }
#pragma unroll
    for (int j = 0; j < 8; ++j) {
        acc[j] += __shfl_xor(acc[j], 16, 64);
        acc[j] += __shfl_xor(acc[j], 32, 64);
    }
    if (sub == 0) {
        int dg = end - start;
        unsigned int o[4];
#pragma unroll
        for (int k = 0; k < 4; ++k) {
            float a0 = (dg > 0) ? __logf(fmaxf(acc[2 * k],     EPS)) : 0.f;
            float a1 = (dg > 0) ? __logf(fmaxf(acc[2 * k + 1], EPS)) : 0.f;
            o[k] = (unsigned int)f2bf(a0) | ((unsigned int)f2bf(a1) << 16);
        }
        *(uint4*)(A + (ll)n * 256 + 128 + c16 * 8) = make_uint4(o[0], o[1], o[2], o[3]);
    }
}

// MFMA GEMM + LayerNorm + ReLU.  A (bf16 [N][256]) aliases out (f32 [N][128]).
__global__ __launch_bounds__(256) void k_gemm_mfma(
        const unsigned short* __restrict__ A,
        const unsigned short* __restrict__ WT,
        const float* __restrict__ bias,
        const float* __restrict__ gamma,
        const float* __restrict__ beta,
        float* __restrict__ out, int N) {
    __shared__ unsigned char sA[64 * 512];
    __shared__ float2 sPart[2][64];
    int t = threadIdx.x;
    int l = t & 63, w = t >> 6;
    int wr = w >> 1, wc = w & 1;
    int n0 = blockIdx.x * 64;

    const uint4* gA = (const uint4*)(A + (ll)n0 * 256);
#pragma unroll
    for (int i = 0; i < 8; ++i) {
        int c = i * 256 + t;
        int row = c >> 5, cc = c & 31;
        uint4 v = make_uint4(0u, 0u, 0u, 0u);
        if (n0 + row < N) v = gA[row * 32 + cc];
        *(uint4*)(sA + row * 512 + ((cc * 16) ^ ((row & 7) << 4))) = v;
    }
    __syncthreads();

    f32x4 acc[2][4];
#pragma unroll
    for (int m = 0; m < 2; ++m)
#pragma unroll
        for (int n = 0; n < 4; ++n) acc[m][n] = (f32x4){0.f, 0.f, 0.f, 0.f};

    const int lr = l & 15, lk = l >> 4;
    const int aswz = (lr & 7) << 4;
    const unsigned short* wbase = WT + (wc * 64 + lr) * 256 + lk * 8;

#pragma unroll
    for (int ks = 0; ks < 8; ++ks) {
        short8 a[2], b[4];
#pragma unroll
        for (int m = 0; m < 2; ++m) {
            int arow = wr * 32 + m * 16 + lr;
            a[m] = *(const short8*)(sA + arow * 512 + ((ks * 64 + lk * 16) ^ aswz));
        }
#pragma unroll
        for (int n = 0; n < 4; ++n)
            b[n] = *(const short8*)(wbase + n * 16 * 256 + ks * 32);
#pragma unroll
        for (int m = 0; m < 2; ++m)
#pragma unroll
            for (int n = 0; n < 4; ++n)
                acc[m][n] = __builtin_amdgcn_mfma_f32_16x16x32_bf16(a[m], b[n], acc[m][n], 0, 0, 0);
    }

    const int col_base = wc * 64 + lr;
    float bn[4], gn[4], ben[4];
#pragma unroll
    for (int n = 0; n < 4; ++n) {
        int col = col_base + n * 16;
        bn[n] = bias[col]; gn[n] = gamma[col]; ben[n] = beta[col];
    }
#pragma unroll
    for (int m = 0; m < 2; ++m) {
#pragma unroll
        for (int r = 0; r < 4; ++r) {
            float s = 0.f, q = 0.f;
#pragma unroll
            for (int n = 0; n < 4; ++n) {
                float v = acc[m][n][r] + bn[n];
                acc[m][n][r] = v;
                s += v; q += v * v;
            }
#pragma unroll
            for (int o = 1; o < 16; o <<= 1) {
                s += __shfl_xor(s, o, 64);
                q += __shfl_xor(q, o, 64);
            }
            if (lr == 0) {
                int rowl = wr * 32 + m * 16 + lk * 4 + r;
                sPart[wc][rowl] = make_float2(s, q);
            }
        }
    }
    __syncthreads();
#pragma unroll
    for (int m = 0; m < 2; ++m) {
#pragma unroll
        for (int r = 0; r < 4; ++r) {
            int rowl = wr * 32 + m * 16 + lk * 4 + r;
            float2 p0 = sPart[0][rowl], p1 = sPart[1][rowl];
            float ssum = p0.x + p1.x, qsum = p0.y + p1.y;
            float mean = ssum * (1.f / 128.f);
            float var  = qsum * (1.f / 128.f) - mean * mean;
            float rstd = rsqrtf(var + LN_EPS);
            int grow = n0 + rowl;
            if (grow < N) {
                float* op = out + (ll)grow * 128;
#pragma unroll
                for (int n = 0; n < 4; ++n) {
                    float y = (acc[m][n][r] - mean) * rstd * gn[n] + ben[n];
                    op[col_base + n * 16] = fmaxf(y, 0.f);
                }
            }
        }
    }
}

// ======================= mid path (round-3 counting sort) =======================

__global__ __launch_bounds__(256) void k_hist(const void* __restrict__ edst,
                                              int* __restrict__ deg, int E, int N) {
    bool is64 = idx_is_i64(edst, N);
    int i = blockIdx.x * 256 + threadIdx.x;
    if (i < E) atomicAdd(&deg[load_idx(edst, i, is64)], 1);
}

__global__ __launch_bounds__(256) void k_scanA(const int* __restrict__ deg,
                                               int* __restrict__ off,
                                               int* __restrict__ bsum, int N) {
    __shared__ int s[256];
    int b = blockIdx.x, t = threadIdx.x;
    int base = b * 1024 + t * 4;
    int v0 = 0, v1 = 0, v2 = 0, v3 = 0;
    if (base + 0 < N) v0 = deg[base + 0];
    if (base + 1 < N) v1 = deg[base + 1];
    if (base + 2 < N) v2 = deg[base + 2];
    if (base + 3 < N) v3 = deg[base + 3];
    int loc = v0 + v1 + v2 + v3;
    s[t] = loc;
    __syncthreads();
    for (int o = 1; o < 256; o <<= 1) {
        int xv = (t >= o) ? s[t - o] : 0;
        __syncthreads();
        s[t] += xv;
        __syncthreads();
    }
    int run = s[t] - loc;
    if (t == 255) bsum[b] = s[255];
    if (base + 0 < N) off[base + 0] = run; run += v0;
    if (base + 1 < N) off[base + 1] = run; run += v1;
    if (base + 2 < N) off[base + 2] = run; run += v2;
    if (base + 3 < N) off[base + 3] = run;
}

__global__ __launch_bounds__(256) void k_scanB(const int* __restrict__ bsum,
                                               int* __restrict__ bbase, int NB) {
    __shared__ int s[256];
    int t = threadIdx.x;
    int v = (t < NB) ? bsum[t] : 0;
    s[t] = v;
    __syncthreads();
    for (int o = 1; o < 256; o <<= 1) {
        int xv = (t >= o) ? s[t - o] : 0;
        __syncthreads();
        s[t] += xv;
        __syncthreads();
    }
    if (t < NB) bbase[t] = s[t] - v;
}

__global__ __launch_bounds__(256) void k_scanC(int* __restrict__ off,
                                               int* __restrict__ cur,
                                               const int* __restrict__ bbase, int N, int E) {
    int b = blockIdx.x, t = threadIdx.x;
    int add = bbase[b];
    int base = b * 1024 + t * 4;
#pragma unroll
    for (int i = 0; i < 4; ++i) {
        int idx = base + i;
        if (idx < N) {
            int o = off[idx] + add;
            off[idx] = o;
            cur[idx] = o;
        }
    }
    if (b == 0 && t == 0) off[N] = E;
}

__global__ __launch_bounds__(256) void k_scatter32(const void* __restrict__ esrc,
                                                   const void* __restrict__ edst,
                                                   int* __restrict__ cur,
                                                   unsigned short* __restrict__ bucket,
                                                   int E, int N) {
    bool is64s = idx_is_i64(esrc, N);
    bool is64d = idx_is_i64(edst, N);
    int i = blockIdx.x * 256 + threadIdx.x;
    if (i < E) {
        int s = load_idx(esrc, i, is64s);
        int d = load_idx(edst, i, is64d);
        int pos = atomicAdd(&cur[d], 1);
        bucket[pos] = (unsigned short)s;
    }
}

// ======================= fallback (atomic) path =======================

__global__ __launch_bounds__(256) void scatter_expsum(
        const float* __restrict__ x, const void* __restrict__ esrc_raw,
        const void* __restrict__ edst_raw, float* __restrict__ sumexp,
        int* __restrict__ deg, int E, int N) {
    ll tid = (ll)blockIdx.x * blockDim.x + threadIdx.x;
    ll total = (ll)E * 32;
    if (tid >= total) return;
    bool is64 = idx_is_i64(esrc_raw, N);
    ll e = tid >> 5;
    int q = (int)(tid & 31);
    int s = load_idx(esrc_raw, e, is64);
    int d = load_idx(edst_raw, e, is64);
    const float4 v = *reinterpret_cast<const float4*>(x + (ll)s * D + q * 4);
    float* outp = sumexp + (ll)d * D + q * 4;
    atomicAdd(outp + 0, expf(v.x));
    atomicAdd(outp + 1, expf(v.y));
    atomicAdd(outp + 2, expf(v.z));
    atomicAdd(outp + 3, expf(v.w));
    if (q == 0) atomicAdd(deg + d, 1);
}

__global__ __launch_bounds__(128) void gemm_ln_relu_fb(
        const float* __restrict__ x, const float* __restrict__ sumexp,
        const int* __restrict__ deg, const float* __restrict__ W,
        const float* __restrict__ bias, const float* __restrict__ gamma,
        const float* __restrict__ beta, float* __restrict__ out) {
    const int n = blockIdx.x;
    const int t = threadIdx.x;
    __shared__ float v[2 * D];
    __shared__ float s_sum[2], s_sq[2];
    v[t] = x[(ll)n * D + t];
    float se = sumexp[(ll)n * D + t];
    v[D + t] = (deg[n] > 0) ? logf(fmaxf(se, EPS)) : 0.0f;
    __syncthreads();
    float acc = bias[t];
#pragma unroll 8
    for (int k = 0; k < 2 * D; ++k) acc += v[k] * W[k * D + t];
    float sum = acc, sq = acc * acc;
#pragma unroll
    for (int o = 32; o > 0; o >>= 1) {
        sum += __shfl_xor(sum, o, 64);
        sq  += __shfl_xor(sq, o, 64);
    }
    int w = t >> 6;
    if ((t & 63) == 0) { s_sum[w] = sum; s_sq[w] = sq; }
    __syncthreads();
    float mean = (s_sum[0] + s_sum[1]) * (1.0f / D);
    float var  = (s_sq[0] + s_sq[1]) * (1.0f / D) - mean * mean;
    float r = rsqrtf(var + LN_EPS);
    float y = (acc - mean) * r * gamma[t] + beta[t];
    out[(ll)n * D + t] = fmaxf(y, 0.0f);
}

// mid-path aggregate (reads f32 x, writes A) — kept for the mid fallback
__global__ __launch_bounds__(128) void k_aggregate_mid(const float* __restrict__ x,
                                                       const unsigned short* __restrict__ bucket,
                                                       const int* __restrict__ off,
                                                       unsigned short* __restrict__ A, int N) {
    int n = blockIdx.x, t = threadIdx.x;
    int start = __builtin_amdgcn_readfirstlane(off[n]);
    int end   = __builtin_amdgcn_readfirstlane(off[n + 1]);
    float acc = 0.f;
    for (int e = start; e < end; ++e) {
        int s0 = bucket[e];
        acc += __expf(x[(ll)s0 * D + t]);
    }
    float agg = (end > start) ? __logf(fmaxf(acc, EPS)) : 0.f;
    A[(ll)n * 256 + t]       = f2bf(x[(ll)n * D + t]);
    A[(ll)n * 256 + 128 + t] = f2bf(agg);
}

// ======================= launch =======================

extern "C" void kernel_launch(void* const* d_in, const int* in_sizes, int n_in,
                              void* d_out, int out_size, void* d_ws, size_t ws_size,
                              hipStream_t stream) {
    const float* x     = (const float*)d_in[0];
    const void*  esrc  = d_in[1];
    const void*  edst  = d_in[2];
    const float* W     = (const float*)d_in[3];
    const float* bias  = (const float*)d_in[4];
    const float* gamma = (const float*)d_in[5];
    const float* beta  = (const float*)d_in[6];

    const int E = in_sizes[1];
    const int N = in_sizes[0] / D;
    float* out = (float*)d_out;
    unsigned short* A = (unsigned short*)d_out;

    // workspace layout (fast path)
    // off[N+1] | bincnt[128] | pbase[129] | pcur[128] | pairs[E] u32 | bucket[E] u16 | wt 64KB
    size_t need_fast = ((size_t)(N + 1) + 128 + 129 + 128 + (size_t)E) * 4
                     + (size_t)E * 2 + 2 + 65536;
    const int NB = (N + 1023) / 1024;
    size_t need_mid = ((size_t)3 * N + 1 + 512 + 16384) * 4 + (size_t)E * 2 + 2;

    if (N <= 65536 && ws_size >= need_fast) {
        int* off            = (int*)d_ws;
        int* bincnt         = off + (N + 1);
        int* pbase          = bincnt + 128;
        int* pcur           = pbase + 129;
        unsigned int* pairs = (unsigned int*)(pcur + 128);
        unsigned short* bucket = (unsigned short*)(pairs + E);
        unsigned short* wt  = (unsigned short*)((char*)(bucket + E) + (((size_t)(bucket + E)) & 2 ? 2 : 0));

        const int NBIN = (N + BINW - 1) >> BINSHIFT;
        const int EB = (E + P1_EPB - 1) / P1_EPB;

        hipMemsetAsync(bincnt, 0, 128 * sizeof(int), stream);
        k_prep<<<(N * 32 + 255) / 256, 256, 0, stream>>>(x, A, N);
        k_wt<<<128, 256, 0, stream>>>(W, wt);
        k_pass1a<<<EB, 256, 0, stream>>>(edst, bincnt, E, N);
        k_binscan<<<1, NBIN_MAX, 0, stream>>>(bincnt, pbase, pcur, off, E, N);
        k_pass1b<<<EB, 256, 0, stream>>>(esrc, edst, pcur, pairs, E, N);
        k_pass2<<<NBIN, 256, 0, stream>>>(pairs, pbase, off, bucket, N);
        k_aggregate<<<(N + 3) / 4, 256, 0, stream>>>(off, bucket, A, N);
        k_gemm_mfma<<<(N + 63) / 64, 256, 0, stream>>>(A, wt, bias, gamma, beta, out, N);
    } else if (N <= 65536 && ws_size >= need_mid && NB <= 256) {
        int* deg    = (int*)d_ws;
        int* off    = deg + N;
        int* cur    = off + (N + 1);
        int* bsum   = cur + N;
        int* bbase  = bsum + 256;
        unsigned short* wt = (unsigned short*)(bbase + 256);
        unsigned short* bucket = wt + 32768;

        hipMemsetAsync(deg, 0, (size_t)N * sizeof(int), stream);
        int eb = (E + 255) / 256;
        k_wt<<<128, 256, 0, stream>>>(W, wt);
        k_hist<<<eb, 256, 0, stream>>>(edst, deg, E, N);
        k_scanA<<<NB, 256, 0, stream>>>(deg, off, bsum, N);
        k_scanB<<<1, 256, 0, stream>>>(bsum, bbase, NB);
        k_scanC<<<NB, 256, 0, stream>>>(off, cur, bbase, N, E);
        k_scatter32<<<eb, 256, 0, stream>>>(esrc, edst, cur, bucket, E, N);
        k_aggregate_mid<<<N, 128, 0, stream>>>(x, bucket, off, A, N);
        k_gemm_mfma<<<(N + 63) / 64, 256, 0, stream>>>(A, wt, bias, gamma, beta, out, N);
    } else {
        float* sumexp = out;
        int* deg = (int*)d_ws;
        hipMemsetAsync(sumexp, 0, (size_t)N * D * sizeof(float), stream);
        hipMemsetAsync(deg, 0, (size_t)N * sizeof(int), stream);
        ll total = (ll)E * 32;
        int blocks = (int)((total + 255) / 256);
        scatter_expsum<<<blocks, 256, 0, stream>>>(x, esrc, edst, sumexp, deg, E, N);
        gemm_ln_relu_fb<<<N, D, 0, stream>>>(x, sumexp, deg, W, bias, gamma, beta, out);
    }
}